// Round 6
// baseline (411.783 us; speedup 1.0000x reference)
//
#include <hip/hip_runtime.h>
#include <hip/hip_bf16.h>

typedef __bf16 bf16_t;
typedef __attribute__((ext_vector_type(8))) __bf16 bf16x8;
typedef __attribute__((ext_vector_type(4))) __bf16 bf16x4;
typedef __attribute__((ext_vector_type(4))) float floatx4;
typedef __attribute__((ext_vector_type(4))) int intx4;

#define NN 8192
#define FIN 256
#define FOUT 64
#define GAT_ALPHA 0.2f
#define NSLICE 8
#define JS (NN / NSLICE)     // 1024 j per slice
#define NJB (JS / 32)        // 32 MFMA K-tiles per slice
#define IB 64                // i-rows per block

// global_load_lds: wave-uniform LDS base, per-lane global src, 16B/lane
typedef const __attribute__((address_space(1))) void gv_t;
typedef __attribute__((address_space(3))) void lv_t;
#define GLOAD16(gp, lp) \
    __builtin_amdgcn_global_load_lds((gv_t*)(gp), (lv_t*)(lp), 16, 0, 0)

// ---------------------------------------------------------------------------
// Kernel A: h = input @ W (fp32 in -> bf16 MFMA). Stores h in MFMA
// B-FRAGMENT layout hTf[jb][ft][lane][8]: element (jb,ft,lq,lm,e) =
// h[jb*32 + lq*8 + e][ft*16 + lm]. A wave's B-frag load in kernel B is then
// a single contiguous 1KB global read. Also emits per-row E=exp(s),
// F=exp(0.2 s) for both attention halves.  (unchanged)
// ---------------------------------------------------------------------------
__global__ __launch_bounds__(256) void gat_h_kernel(
    const float* __restrict__ input,    // [8192][256] fp32
    const float* __restrict__ W,        // [256][64] fp32
    const float* __restrict__ a,        // [128] fp32
    bf16_t* __restrict__ hTf,           // [256][4][64][8] bf16 frag layout
    float* __restrict__ e1g, float* __restrict__ f1g,
    float* __restrict__ e2g, float* __restrict__ f2g)
{
    alignas(16) __shared__ bf16_t in_lds[32][264];  // input tile, K contiguous
    alignas(16) __shared__ bf16_t wt_lds[64][264];  // W transposed [f][k]
    __shared__ float h_lds[32][65];                 // h tile fp32 for s1/s2

    const int t  = threadIdx.x;
    const int i0 = blockIdx.x * 32;

    #pragma unroll
    for (int v = 0; v < 8; v++) {
        int u  = v * 256 + t;
        int i  = u >> 6;
        int k4 = (u & 63) * 4;
        floatx4 x = *(const floatx4*)(input + (size_t)(i0 + i) * FIN + k4);
        bf16x4 b;
        #pragma unroll
        for (int e = 0; e < 4; e++) b[e] = (bf16_t)x[e];
        *(bf16x4*)(&in_lds[i][k4]) = b;
    }
    #pragma unroll
    for (int v = 0; v < 16; v++) {
        int u  = v * 256 + t;
        int k  = u >> 4;
        int f4 = (u & 15) * 4;
        floatx4 wv = *(const floatx4*)(W + k * FOUT + f4);
        #pragma unroll
        for (int e = 0; e < 4; e++) wt_lds[f4 + e][k] = (bf16_t)wv[e];
    }
    __syncthreads();

    const int wave = t >> 6;
    const int lane = t & 63;
    const int i16  = (wave & 1) * 16;
    const int f32  = (wave >> 1) * 32;
    const int lm   = lane & 15;
    const int lq   = lane >> 4;

    floatx4 acc0 = {0.f, 0.f, 0.f, 0.f};
    floatx4 acc1 = {0.f, 0.f, 0.f, 0.f};
    #pragma unroll
    for (int ks = 0; ks < 8; ks++) {
        int ko = ks * 32 + lq * 8;
        bf16x8 af = *(const bf16x8*)(&in_lds[i16 + lm][ko]);
        bf16x8 b0 = *(const bf16x8*)(&wt_lds[f32 + lm][ko]);
        bf16x8 b1 = *(const bf16x8*)(&wt_lds[f32 + 16 + lm][ko]);
        acc0 = __builtin_amdgcn_mfma_f32_16x16x32_bf16(af, b0, acc0, 0, 0, 0);
        acc1 = __builtin_amdgcn_mfma_f32_16x16x32_bf16(af, b1, acc1, 0, 0, 0);
    }

    // store hTf fragment layout. Lane holds h[i0+i16+lq*4+r][f32+c*16+lm];
    // frag coords: jb=i0/32, ft=f32/16+c, lq'=(i16+lq*4)/8, e=(lq&1)*4+r.
    {
        const int jb  = i0 >> 5;
        const int lqp = (i16 >> 3) + (lq >> 1);
        const int e0  = (lq & 1) * 4;
        #pragma unroll
        for (int c = 0; c < 2; c++) {
            floatx4 acc = c ? acc1 : acc0;
            int ft = (f32 >> 4) + c;
            bf16x4 hp;
            #pragma unroll
            for (int r = 0; r < 4; r++) hp[r] = (bf16_t)acc[r];
            *(bf16x4*)(hTf + (size_t)(((jb * 4 + ft) * 64 + lqp * 16 + lm) * 8 + e0)) = hp;
        }
    }
    // fp32 h tile into LDS for s1/s2
    #pragma unroll
    for (int c = 0; c < 2; c++) {
        floatx4 acc = c ? acc1 : acc0;
        #pragma unroll
        for (int r = 0; r < 4; r++)
            h_lds[i16 + lq * 4 + r][f32 + c * 16 + lm] = acc[r];
    }
    __syncthreads();

    if (t < 64) {
        int r   = t & 31;
        int sel = t >> 5;
        const float* av = a + sel * FOUT;
        float s = 0.f;
        #pragma unroll 8
        for (int f = 0; f < FOUT; f++) s += h_lds[r][f] * av[f];
        int gi = i0 + r;
        float E = expf(s);
        float F = expf(GAT_ALPHA * s);
        if (sel == 0) { e1g[gi] = E; f1g[gi] = F; }
        else          { e2g[gi] = E; f2g[gi] = F; }
    }
}

// ---------------------------------------------------------------------------
// Kernel B: fused pack + attention + aggregation.
// PHASE 1 (stream+pack): each wave streams its own 16 adj rows x 1024-j
// window with the m13 copy pattern -- lane-consecutive intx4 (1KB
// contiguous per wave-instruction, 4 lanes/64B line), 64 loads/wave, no
// barriers, 16 independent waves/CU. In-register bit-pack: 4 cmps ->
// nibble, shfl_xor(1) merges lane pairs, even lanes write one byte to the
// XOR-swizzled bitsL slot. adj is read exactly ONCE grid-wide.
// PHASE 2 (compute): identical to R5 -- bits from LDS (2-way/free reads),
// e2/f2 from LDS, hTf B-frags straight from global (1MB, L2-hot,
// contiguous 1KB per wave-load), 5th MFMA vs all-ones for rowsum.
// LDS = 16 KB; grid (128, 8) = 1024 blocks = 4/CU resident, 16 waves/CU.
// ---------------------------------------------------------------------------
__global__ __launch_bounds__(256, 4) void gat_att_kernel(
    const int* __restrict__ adj,             // [8192][8192] int32
    const bf16_t* __restrict__ hTf,          // [256][4][64][8] bf16 frag
    const float* __restrict__ e1g, const float* __restrict__ f1g,
    const float* __restrict__ e2g, const float* __restrict__ f2g,
    float* __restrict__ pacc,                // [NSLICE][8192][64] fp32
    float* __restrict__ prs)                 // [NSLICE][8192] fp32
{
    __shared__ unsigned char bitsL[IB][128];    // 8 KB, XOR-swizzled granules
    __shared__ float e2l[JS], f2l[JS];          // 8 KB

    const int t     = threadIdx.x;
    const int i0    = blockIdx.x * IB;
    const int slice = blockIdx.y;
    const int jbase = slice * JS;

    const int wave = t >> 6;
    const int lane = t & 63;
    const int lm   = lane & 15;
    const int lq   = lane >> 4;

    // ---- stage e2/f2 slice (1 KB per wave each, linear) ----
    {
        int o = wave * 256;
        GLOAD16(e2g + jbase + o + lane * 4, e2l + o);
        GLOAD16(f2g + jbase + o + lane * 4, f2l + o);
    }

    // ---- PHASE 1: stream adj (m13 pattern) + pack bits into bitsL ----
    // Wave w packs rows w*16 .. w*16+15 (the same rows it computes on).
    // instr idx = wave*64+k: row r = idx>>2, quarter q = idx&3;
    // lane l covers j = q*256 + l*4 .. +3  ->  nibble; lane pair -> byte.
    #pragma unroll 8
    for (int k = 0; k < 64; k++) {
        const int idx = wave * 64 + k;
        const int r   = idx >> 2;           // block-local row
        const int q   = idx & 3;            // quarter of the 1024-j window
        intx4 v = *(const intx4*)(adj + (size_t)(i0 + r) * NN
                                      + jbase + q * 256 + lane * 4);
        unsigned nib = (v[0] > 0 ? 1u : 0u) | (v[1] > 0 ? 2u : 0u)
                     | (v[2] > 0 ? 4u : 0u) | (v[3] > 0 ? 8u : 0u);
        unsigned pn  = (unsigned)__shfl_xor((int)nib, 1);
        if (!(lane & 1)) {
            unsigned char byte = (unsigned char)(nib | (pn << 4));
            int bIdx = q * 32 + (lane >> 1);             // byte index in row
            int swz  = (((bIdx >> 4) ^ (r & 7)) << 4) | (bIdx & 15);
            bitsL[r][swz] = byte;
        }
    }
    __syncthreads();    // pack visible + drains e2/f2 vmcnt; only barrier

    // ---- PHASE 2: compute (identical to R5) ----
    const int   row = wave * 16 + lm;          // block-local A-frag row
    const float E1  = e1g[i0 + row];
    const float F1  = f1g[i0 + row];

    floatx4 acc0 = {0.f,0.f,0.f,0.f}, acc1 = {0.f,0.f,0.f,0.f};
    floatx4 acc2 = {0.f,0.f,0.f,0.f}, acc3 = {0.f,0.f,0.f,0.f};
    floatx4 accR = {0.f,0.f,0.f,0.f};
    bf16x8 ones;
    #pragma unroll
    for (int e = 0; e < 8; e++) ones[e] = (bf16_t)1.0f;

    const bf16_t* hslice = hTf + (size_t)slice * NJB * 2048 + (size_t)lane * 8;

    #pragma unroll 8
    for (int jb = 0; jb < NJB; jb++) {
        // word jb of this row's bit-window (granule-XOR read, 2-way = free)
        int off = (((jb >> 2) ^ (row & 7)) << 4) | ((jb & 3) << 2);
        int wrd = *(const int*)(&bitsL[row][off]);
        unsigned bt = ((unsigned)wrd >> (lq * 8)) & 0xffu;   // v_bfe

        int jo = jb * 32 + lq * 8;
        floatx4 e2a = *(const floatx4*)(&e2l[jo]);
        floatx4 e2b = *(const floatx4*)(&e2l[jo + 4]);
        floatx4 f2a = *(const floatx4*)(&f2l[jo]);
        floatx4 f2b = *(const floatx4*)(&f2l[jo + 4]);
        bf16x8 frag;
        #pragma unroll
        for (int e = 0; e < 4; e++) {
            float w0 = fmaxf(E1 * e2a[e], F1 * f2a[e]);
            frag[e]     = (bt & (1u << e))       ? (bf16_t)w0 : (bf16_t)0.f;
            float w1 = fmaxf(E1 * e2b[e], F1 * f2b[e]);
            frag[e + 4] = (bt & (1u << (e + 4))) ? (bf16_t)w1 : (bf16_t)0.f;
        }

        // B-frags: contiguous 1KB per wave from frag-layout hT (L2/L1-hot)
        const bf16_t* hb = hslice + (size_t)jb * 2048;
        bf16x8 b0 = *(const bf16x8*)(hb);
        bf16x8 b1 = *(const bf16x8*)(hb + 512);
        bf16x8 b2 = *(const bf16x8*)(hb + 1024);
        bf16x8 b3 = *(const bf16x8*)(hb + 1536);
        acc0 = __builtin_amdgcn_mfma_f32_16x16x32_bf16(frag, b0, acc0, 0, 0, 0);
        acc1 = __builtin_amdgcn_mfma_f32_16x16x32_bf16(frag, b1, acc1, 0, 0, 0);
        acc2 = __builtin_amdgcn_mfma_f32_16x16x32_bf16(frag, b2, acc2, 0, 0, 0);
        acc3 = __builtin_amdgcn_mfma_f32_16x16x32_bf16(frag, b3, acc3, 0, 0, 0);
        accR = __builtin_amdgcn_mfma_f32_16x16x32_bf16(frag, ones, accR, 0, 0, 0);
    }

    // ---- rowsum write: accR col-independent; lm==0 lanes write ----
    if (lm == 0) {
        #pragma unroll
        for (int r = 0; r < 4; r++)
            prs[(size_t)slice * NN + i0 + wave * 16 + lq * 4 + r] = accR[r];
    }

    // ---- partial acc write: D layout col = ft*16+lm, row = lq*4+r ----
    float* pa = pacc + (size_t)slice * NN * FOUT
                     + (size_t)(i0 + wave * 16) * FOUT;
    #pragma unroll
    for (int ft = 0; ft < 4; ft++) {
        floatx4 acc = (ft == 0) ? acc0 : (ft == 1) ? acc1
                    : (ft == 2) ? acc2 : acc3;
        #pragma unroll
        for (int r = 0; r < 4; r++)
            pa[(size_t)(lq * 4 + r) * FOUT + ft * 16 + lm] = acc[r];
    }
}

// ---------------------------------------------------------------------------
// Kernel C: combine NSLICE partials, normalize, ELU, store fp32 output.
// ---------------------------------------------------------------------------
__global__ __launch_bounds__(256) void gat_combine_kernel(
    const float* __restrict__ pacc,     // [NSLICE][8192][64]
    const float* __restrict__ prs,      // [NSLICE][8192]
    float* __restrict__ out)            // [8192][64]
{
    int idx = blockIdx.x * 256 + threadIdx.x;
    int i   = idx >> 4;
    floatx4 s = {0.f, 0.f, 0.f, 0.f};
    float rs  = 0.f;
    #pragma unroll
    for (int p = 0; p < NSLICE; p++) {
        floatx4 v = *(const floatx4*)(pacc + (size_t)p * NN * FOUT + (size_t)idx * 4);
        s += v;
        rs += prs[p * NN + i];
    }
    float rinv = (rs > 0.f) ? 1.0f / rs : 0.f;
    floatx4 r;
    #pragma unroll
    for (int e = 0; e < 4; e++) {
        float x = s[e] * rinv;
        r[e] = (x > 0.f) ? x : (expf(x) - 1.0f);
    }
    *(floatx4*)(out + (size_t)idx * 4) = r;
}

// ---------------------------------------------------------------------------
extern "C" void kernel_launch(void* const* d_in, const int* in_sizes, int n_in,
                              void* d_out, int out_size, void* d_ws, size_t ws_size,
                              hipStream_t stream) {
    const float* input = (const float*)d_in[0];     // [8192][256] fp32
    const int*   adj   = (const int*)d_in[1];       // [8192][8192] int32
    const float* W     = (const float*)d_in[2];     // [256][64] fp32
    const float* a     = (const float*)d_in[3];     // [128] fp32
    float*       out   = (float*)d_out;             // [8192][64] fp32

    char* ws = (char*)d_ws;
    bf16_t* hTf = (bf16_t*)ws;                      // 1 MiB (frag layout)
    float*  e1g = (float*)(ws + (1 << 20));
    float*  f1g = e1g + NN;
    float*  e2g = f1g + NN;
    float*  f2g = e2g + NN;
    float*  pacc = f2g + NN;                        // 16 MiB
    float*  prs  = pacc + (size_t)NSLICE * NN * FOUT;   // 256 KiB

    gat_h_kernel<<<NN / 32, 256, 0, stream>>>(input, W, a, hTf,
                                              e1g, f1g, e2g, f2g);
    dim3 gridB(NN / IB, NSLICE);
    gat_att_kernel<<<gridB, 256, 0, stream>>>(adj, hTf,
                                              e1g, f1g, e2g, f2g, pacc, prs);
    gat_combine_kernel<<<NN * FOUT / 4 / 256, 256, 0, stream>>>(pacc, prs, out);
}

// Round 7
// 400.747 us; speedup vs baseline: 1.0275x; 1.0275x over previous
//
#include <hip/hip_runtime.h>
#include <hip/hip_bf16.h>

typedef __bf16 bf16_t;
typedef __attribute__((ext_vector_type(8))) __bf16 bf16x8;
typedef __attribute__((ext_vector_type(4))) __bf16 bf16x4;
typedef __attribute__((ext_vector_type(4))) float floatx4;
typedef __attribute__((ext_vector_type(4))) int intx4;

#define NN 8192
#define FIN 256
#define FOUT 64
#define GAT_ALPHA 0.2f
#define NSLICE 8
#define JS (NN / NSLICE)     // 1024 j per slice
#define NJB (JS / 32)        // 32 MFMA K-tiles per slice
#define IB 64                // i-rows per block

// Permuted j-order ("jv"): real j = G*256 + p*4 + w  <->  jv = G*256 + w*64 + p.
// This is ballot-natural: word w of group G has bit p = adj[G*256+p*4+w].
// Softmax num/denom sum over j, so a global j-permutation is exact as long as
// adj-bits, e2/f2, and h rows all use the same order. prs/pacc unaffected.

// global_load_lds: wave-uniform LDS base, per-lane global src, 16B/lane
typedef const __attribute__((address_space(1))) void gv_t;
typedef __attribute__((address_space(3))) void lv_t;
#define GLOAD16(gp, lp) \
    __builtin_amdgcn_global_load_lds((gv_t*)(gp), (lv_t*)(lp), 16, 0, 0)

// ---------------------------------------------------------------------------
// Kernel P: ballot pack. adj (256 MB int32) -> bit matrix [8192][128] u64 in
// jv-order. Near-zero processing: per 1 KB wave-read, 4 v_cmp (ballots) +
// ~8 select VALU; one coalesced 512 B store per 16 KB. One wave per row,
// 2048 blocks (~8/CU, 32 waves/CU). This is the decisive read-BW probe.
// ---------------------------------------------------------------------------
__global__ __launch_bounds__(256) void gat_pack_kernel(
    const int* __restrict__ adj,
    unsigned long long* __restrict__ bits)      // [8192][128] u64, jv-order
{
    const int wave = threadIdx.x >> 6;
    const int lane = threadIdx.x & 63;
    const int row  = blockIdx.x * 4 + wave;
    const int* rp  = adj + (size_t)row * NN;

    #pragma unroll
    for (int half = 0; half < 2; half++) {      // 16 groups = 16 KB each
        unsigned long long acc = 0;
        #pragma unroll
        for (int g2 = 0; g2 < 16; g2++) {
            intx4 v = *(const intx4*)(rp + (half * 16 + g2) * 256 + lane * 4);
            unsigned long long m0 = __ballot(v[0] > 0);
            unsigned long long m1 = __ballot(v[1] > 0);
            unsigned long long m2 = __ballot(v[2] > 0);
            unsigned long long m3 = __ballot(v[3] > 0);
            if ((lane >> 2) == g2) {
                unsigned long long m = (lane & 1)
                    ? ((lane & 2) ? m3 : m1)
                    : ((lane & 2) ? m2 : m0);
                acc = m;
            }
        }
        // lane = g2*4 + w  ->  u64 index G_global*4 + w  (G = half*16+g2)
        bits[(size_t)row * 128 + half * 64 + lane] = acc;
    }
}

// ---------------------------------------------------------------------------
// Kernel A: h = input @ W (fp32 in -> bf16 MFMA). Stores h in jv-PERMUTED
// B-fragment layout hTf[jbv][ft][lane][8]: element (jbv,ft,lq,lm,e) =
// h[ perm(jv = jbv*32+lq*8+e) ][ft*16+lm]. Per-lane 8 scalar bf16 stores
// (A writes only 1 MB; ~1/8 coalescing costs ~2 us). Also emits per-row
// E=exp(s), F=exp(0.2 s).
// ---------------------------------------------------------------------------
__global__ __launch_bounds__(256) void gat_h_kernel(
    const float* __restrict__ input,    // [8192][256] fp32
    const float* __restrict__ W,        // [256][64] fp32
    const float* __restrict__ a,        // [128] fp32
    bf16_t* __restrict__ hTf,           // [256][4][64][8] bf16, jv-frag layout
    float* __restrict__ e1g, float* __restrict__ f1g,
    float* __restrict__ e2g, float* __restrict__ f2g)
{
    alignas(16) __shared__ bf16_t in_lds[32][264];
    alignas(16) __shared__ bf16_t wt_lds[64][264];
    __shared__ float h_lds[32][65];

    const int t  = threadIdx.x;
    const int i0 = blockIdx.x * 32;

    #pragma unroll
    for (int v = 0; v < 8; v++) {
        int u  = v * 256 + t;
        int i  = u >> 6;
        int k4 = (u & 63) * 4;
        floatx4 x = *(const floatx4*)(input + (size_t)(i0 + i) * FIN + k4);
        bf16x4 b;
        #pragma unroll
        for (int e = 0; e < 4; e++) b[e] = (bf16_t)x[e];
        *(bf16x4*)(&in_lds[i][k4]) = b;
    }
    #pragma unroll
    for (int v = 0; v < 16; v++) {
        int u  = v * 256 + t;
        int k  = u >> 4;
        int f4 = (u & 15) * 4;
        floatx4 wv = *(const floatx4*)(W + k * FOUT + f4);
        #pragma unroll
        for (int e = 0; e < 4; e++) wt_lds[f4 + e][k] = (bf16_t)wv[e];
    }
    __syncthreads();

    const int wave = t >> 6;
    const int lane = t & 63;
    const int i16  = (wave & 1) * 16;
    const int f32  = (wave >> 1) * 32;
    const int lm   = lane & 15;
    const int lq   = lane >> 4;

    floatx4 acc0 = {0.f, 0.f, 0.f, 0.f};
    floatx4 acc1 = {0.f, 0.f, 0.f, 0.f};
    #pragma unroll
    for (int ks = 0; ks < 8; ks++) {
        int ko = ks * 32 + lq * 8;
        bf16x8 af = *(const bf16x8*)(&in_lds[i16 + lm][ko]);
        bf16x8 b0 = *(const bf16x8*)(&wt_lds[f32 + lm][ko]);
        bf16x8 b1 = *(const bf16x8*)(&wt_lds[f32 + 16 + lm][ko]);
        acc0 = __builtin_amdgcn_mfma_f32_16x16x32_bf16(af, b0, acc0, 0, 0, 0);
        acc1 = __builtin_amdgcn_mfma_f32_16x16x32_bf16(af, b1, acc1, 0, 0, 0);
    }

    // permuted hTf store. Lane holds h[i0 + d][f32+c*16+lm], d = i16+lq*4+r.
    // j = i0+d: G = i0>>8, w = d&3 = r, p = p0 + (d>>2), p0 = (i0&255)>>2.
    // slot: jbv = G*8 + r*2 + (p0>>5), lq' = (p0>>3)&3, e' = (i16>>2)+lq.
    {
        const int G    = i0 >> 8;
        const int p0   = (i0 & 255) >> 2;
        const int hi5  = p0 >> 5;
        const int lqp  = (p0 >> 3) & 3;
        const int enew = (i16 >> 2) + lq;
        #pragma unroll
        for (int c = 0; c < 2; c++) {
            floatx4 acc = c ? acc1 : acc0;
            int ft = (f32 >> 4) + c;
            #pragma unroll
            for (int r = 0; r < 4; r++) {
                int jbv = G * 8 + r * 2 + hi5;
                size_t idx = ((size_t)(jbv * 4 + ft) * 64 + lqp * 16 + lm) * 8 + enew;
                hTf[idx] = (bf16_t)acc[r];
            }
        }
    }
    // fp32 h tile into LDS for s1/s2
    #pragma unroll
    for (int c = 0; c < 2; c++) {
        floatx4 acc = c ? acc1 : acc0;
        #pragma unroll
        for (int r = 0; r < 4; r++)
            h_lds[i16 + lq * 4 + r][f32 + c * 16 + lm] = acc[r];
    }
    __syncthreads();

    if (t < 64) {
        int r   = t & 31;
        int sel = t >> 5;
        const float* av = a + sel * FOUT;
        float s = 0.f;
        #pragma unroll 8
        for (int f = 0; f < FOUT; f++) s += h_lds[r][f] * av[f];
        int gi = i0 + r;
        float E = expf(s);
        float F = expf(GAT_ALPHA * s);
        if (sel == 0) { e1g[gi] = E; f1g[gi] = F; }
        else          { e2g[gi] = E; f2g[gi] = F; }
    }
}

// ---------------------------------------------------------------------------
// Kernel B: attention + aggregation from the jv-ordered bit matrix.
//  - bits staged once to LDS (8 KB, XOR-16B-granule source swizzle; read
//    code identical to the R5-verified path)
//  - e2/f2 staged once via registers with the jv permutation (conflict-free:
//    thread t elem e -> e2l[(t>>6)*256 + e*64 + (t&63)])
//  - phase-2 compute identical to R5/R6 (verified): w-frag in-register,
//    hTf B-frags straight from global (1 MB, L2-hot, contiguous per wave),
//    5th MFMA vs all-ones for rowsum
// LDS = 16 KB; grid (128, 8) = 1024 blocks = 4/CU, 16 waves/CU.
// ---------------------------------------------------------------------------
__global__ __launch_bounds__(256, 4) void gat_att_kernel(
    const unsigned char* __restrict__ bits,  // [8192][1024] bytes, jv-order
    const bf16_t* __restrict__ hTf,          // [256][4][64][8] bf16 jv-frag
    const float* __restrict__ e1g, const float* __restrict__ f1g,
    const float* __restrict__ e2g, const float* __restrict__ f2g,
    float* __restrict__ pacc,                // [NSLICE][8192][64] fp32
    float* __restrict__ prs)                 // [NSLICE][8192] fp32
{
    __shared__ unsigned char bitsL[IB][128];    // 8 KB, XOR-swizzled granules
    __shared__ float e2l[JS], f2l[JS];          // 8 KB, jv-indexed

    const int t     = threadIdx.x;
    const int i0    = blockIdx.x * IB;
    const int slice = blockIdx.y;
    const int jbase = slice * JS;

    const int wave = t >> 6;
    const int lane = t & 63;
    const int lm   = lane & 15;
    const int lq   = lane >> 4;

    // ---- stage bits: rows i0..i0+63, window = 128 B/row (R5-verified) ----
    #pragma unroll
    for (int h = 0; h < 2; h++) {
        int r0 = wave * 16 + h * 8;            // 8 rows per instr
        int r  = r0 + (lane >> 3);
        int g  = (lane & 7) ^ (r & 7);
        GLOAD16(bits + (size_t)(i0 + r) * 1024 + slice * 128 + g * 16,
                &bitsL[r0][0]);
    }
    // ---- stage e2/f2 with jv permutation (register path, once) ----
    {
        floatx4 ev = *(const floatx4*)(e2g + jbase + t * 4);
        floatx4 fv = *(const floatx4*)(f2g + jbase + t * 4);
        int base = (t >> 6) * 256 + (t & 63);
        #pragma unroll
        for (int e = 0; e < 4; e++) {
            e2l[base + e * 64] = ev[e];
            f2l[base + e * 64] = fv[e];
        }
    }
    __syncthreads();    // pack + LDS writes visible; the only barrier

    const int   row = wave * 16 + lm;          // block-local A-frag row
    const float E1  = e1g[i0 + row];
    const float F1  = f1g[i0 + row];

    floatx4 acc0 = {0.f,0.f,0.f,0.f}, acc1 = {0.f,0.f,0.f,0.f};
    floatx4 acc2 = {0.f,0.f,0.f,0.f}, acc3 = {0.f,0.f,0.f,0.f};
    floatx4 accR = {0.f,0.f,0.f,0.f};
    bf16x8 ones;
    #pragma unroll
    for (int e = 0; e < 8; e++) ones[e] = (bf16_t)1.0f;

    const bf16_t* hslice = hTf + (size_t)slice * NJB * 2048 + (size_t)lane * 8;

    #pragma unroll 8
    for (int jb = 0; jb < NJB; jb++) {
        // u32 word jb of this row's window (granule-XOR read, 2-way = free)
        int off = (((jb >> 2) ^ (row & 7)) << 4) | ((jb & 3) << 2);
        int wrd = *(const int*)(&bitsL[row][off]);
        unsigned bt = ((unsigned)wrd >> (lq * 8)) & 0xffu;   // v_bfe

        int jo = jb * 32 + lq * 8;
        floatx4 e2a = *(const floatx4*)(&e2l[jo]);
        floatx4 e2b = *(const floatx4*)(&e2l[jo + 4]);
        floatx4 f2a = *(const floatx4*)(&f2l[jo]);
        floatx4 f2b = *(const floatx4*)(&f2l[jo + 4]);
        bf16x8 frag;
        #pragma unroll
        for (int e = 0; e < 4; e++) {
            float w0 = fmaxf(E1 * e2a[e], F1 * f2a[e]);
            frag[e]     = (bt & (1u << e))       ? (bf16_t)w0 : (bf16_t)0.f;
            float w1 = fmaxf(E1 * e2b[e], F1 * f2b[e]);
            frag[e + 4] = (bt & (1u << (e + 4))) ? (bf16_t)w1 : (bf16_t)0.f;
        }

        const bf16_t* hb = hslice + (size_t)jb * 2048;
        bf16x8 b0 = *(const bf16x8*)(hb);
        bf16x8 b1 = *(const bf16x8*)(hb + 512);
        bf16x8 b2 = *(const bf16x8*)(hb + 1024);
        bf16x8 b3 = *(const bf16x8*)(hb + 1536);
        acc0 = __builtin_amdgcn_mfma_f32_16x16x32_bf16(frag, b0, acc0, 0, 0, 0);
        acc1 = __builtin_amdgcn_mfma_f32_16x16x32_bf16(frag, b1, acc1, 0, 0, 0);
        acc2 = __builtin_amdgcn_mfma_f32_16x16x32_bf16(frag, b2, acc2, 0, 0, 0);
        acc3 = __builtin_amdgcn_mfma_f32_16x16x32_bf16(frag, b3, acc3, 0, 0, 0);
        accR = __builtin_amdgcn_mfma_f32_16x16x32_bf16(frag, ones, accR, 0, 0, 0);
    }

    if (lm == 0) {
        #pragma unroll
        for (int r = 0; r < 4; r++)
            prs[(size_t)slice * NN + i0 + wave * 16 + lq * 4 + r] = accR[r];
    }

    float* pa = pacc + (size_t)slice * NN * FOUT
                     + (size_t)(i0 + wave * 16) * FOUT;
    #pragma unroll
    for (int ft = 0; ft < 4; ft++) {
        floatx4 acc = (ft == 0) ? acc0 : (ft == 1) ? acc1
                    : (ft == 2) ? acc2 : acc3;
        #pragma unroll
        for (int r = 0; r < 4; r++)
            pa[(size_t)(lq * 4 + r) * FOUT + ft * 16 + lm] = acc[r];
    }
}

// ---------------------------------------------------------------------------
// Kernel C: combine NSLICE partials, normalize, ELU, store fp32 output.
// ---------------------------------------------------------------------------
__global__ __launch_bounds__(256) void gat_combine_kernel(
    const float* __restrict__ pacc,     // [NSLICE][8192][64]
    const float* __restrict__ prs,      // [NSLICE][8192]
    float* __restrict__ out)            // [8192][64]
{
    int idx = blockIdx.x * 256 + threadIdx.x;
    int i   = idx >> 4;
    floatx4 s = {0.f, 0.f, 0.f, 0.f};
    float rs  = 0.f;
    #pragma unroll
    for (int p = 0; p < NSLICE; p++) {
        floatx4 v = *(const floatx4*)(pacc + (size_t)p * NN * FOUT + (size_t)idx * 4);
        s += v;
        rs += prs[p * NN + i];
    }
    float rinv = (rs > 0.f) ? 1.0f / rs : 0.f;
    floatx4 r;
    #pragma unroll
    for (int e = 0; e < 4; e++) {
        float x = s[e] * rinv;
        r[e] = (x > 0.f) ? x : (expf(x) - 1.0f);
    }
    *(floatx4*)(out + (size_t)idx * 4) = r;
}

// ---------------------------------------------------------------------------
extern "C" void kernel_launch(void* const* d_in, const int* in_sizes, int n_in,
                              void* d_out, int out_size, void* d_ws, size_t ws_size,
                              hipStream_t stream) {
    const float* input = (const float*)d_in[0];     // [8192][256] fp32
    const int*   adj   = (const int*)d_in[1];       // [8192][8192] int32
    const float* W     = (const float*)d_in[2];     // [256][64] fp32
    const float* a     = (const float*)d_in[3];     // [128] fp32
    float*       out   = (float*)d_out;             // [8192][64] fp32

    char* ws = (char*)d_ws;
    bf16_t* hTf = (bf16_t*)ws;                      // 1 MiB (jv-frag layout)
    float*  e1g = (float*)(ws + (1 << 20));
    float*  f1g = e1g + NN;
    float*  e2g = f1g + NN;
    float*  f2g = e2g + NN;
    unsigned long long* bitsw = (unsigned long long*)(f2g + NN);   // 8 MiB
    float*  pacc = (float*)((char*)bitsw + (size_t)NN * 128 * 8);  // 16 MiB
    float*  prs  = pacc + (size_t)NSLICE * NN * FOUT;              // 256 KiB

    gat_pack_kernel<<<NN / 4, 256, 0, stream>>>(adj, bitsw);
    gat_h_kernel<<<NN / 32, 256, 0, stream>>>(input, W, a, hTf,
                                              e1g, f1g, e2g, f2g);
    dim3 gridB(NN / IB, NSLICE);
    gat_att_kernel<<<gridB, 256, 0, stream>>>((const unsigned char*)bitsw, hTf,
                                              e1g, f1g, e2g, f2g, pacc, prs);
    gat_combine_kernel<<<NN * FOUT / 4 / 256, 256, 0, stream>>>(pacc, prs, out);
}

// Round 8
// 384.458 us; speedup vs baseline: 1.0711x; 1.0424x over previous
//
#include <hip/hip_runtime.h>
#include <hip/hip_bf16.h>

typedef __bf16 bf16_t;
typedef __attribute__((ext_vector_type(8))) __bf16 bf16x8;
typedef __attribute__((ext_vector_type(4))) __bf16 bf16x4;
typedef __attribute__((ext_vector_type(4))) float floatx4;
typedef __attribute__((ext_vector_type(4))) int intx4;

#define NN 8192
#define FIN 256
#define FOUT 64
#define GAT_ALPHA 0.2f
#define NSLICE 8
#define JS (NN / NSLICE)     // 1024 j per slice
#define NJB (JS / 32)        // 32 MFMA K-tiles per slice
#define IB 64                // i-rows per block

// Permuted j-order ("jv"): real j = G*256 + p*4 + w  <->  jv = G*256 + w*64 + p.
// Ballot-natural; softmax num/denom are j-permutation-invariant as long as
// adj-bits, e2/f2, and h rows share the order. prs/pacc unaffected.

// global_load_lds: wave-uniform LDS base, per-lane global src, 16B/lane
typedef const __attribute__((address_space(1))) void gv_t;
typedef __attribute__((address_space(3))) void lv_t;
#define GLOAD16(gp, lp) \
    __builtin_amdgcn_global_load_lds((gv_t*)(gp), (lv_t*)(lp), 16, 0, 0)

// ---------------------------------------------------------------------------
// Kernel P: ballot pack with NON-TEMPORAL loads. adj (256 MB, zero-reuse)
// -> bit matrix [8192][128] u64 in jv-order. nt bypasses L3/L2 allocation on
// the read-miss path -- the one untested mechanism for the ~2.5 TB/s read
// wall (streaming writes, which pay no allocate, run 6.7 TB/s). Loads are
// batched 4-wide ahead of the ballot chain for issue ILP.
// ---------------------------------------------------------------------------
__global__ __launch_bounds__(256) void gat_pack_kernel(
    const int* __restrict__ adj,
    unsigned long long* __restrict__ bits)      // [8192][128] u64, jv-order
{
    const int wave = threadIdx.x >> 6;
    const int lane = threadIdx.x & 63;
    const int row  = blockIdx.x * 4 + wave;
    const int* rp  = adj + (size_t)row * NN;

    #pragma unroll
    for (int half = 0; half < 2; half++) {      // 16 groups = 16 KB each
        unsigned long long acc = 0;
        #pragma unroll
        for (int gb = 0; gb < 4; gb++) {        // 4 batches x 4 groups
            const int* bp = rp + (half * 16 + gb * 4) * 256 + lane * 4;
            intx4 v0 = __builtin_nontemporal_load((const intx4*)(bp));
            intx4 v1 = __builtin_nontemporal_load((const intx4*)(bp + 256));
            intx4 v2 = __builtin_nontemporal_load((const intx4*)(bp + 512));
            intx4 v3 = __builtin_nontemporal_load((const intx4*)(bp + 768));
            #pragma unroll
            for (int s = 0; s < 4; s++) {
                intx4 v = (s == 0) ? v0 : (s == 1) ? v1 : (s == 2) ? v2 : v3;
                const int g2 = gb * 4 + s;
                unsigned long long m0 = __ballot(v[0] > 0);
                unsigned long long m1 = __ballot(v[1] > 0);
                unsigned long long m2 = __ballot(v[2] > 0);
                unsigned long long m3 = __ballot(v[3] > 0);
                if ((lane >> 2) == g2) {
                    unsigned long long m = (lane & 1)
                        ? ((lane & 2) ? m3 : m1)
                        : ((lane & 2) ? m2 : m0);
                    acc = m;
                }
            }
        }
        // lane = g2*4 + w  ->  u64 index G_global*4 + w  (G = half*16+g2)
        bits[(size_t)row * 128 + half * 64 + lane] = acc;
    }
}

// ---------------------------------------------------------------------------
// Kernel A: h = input @ W (fp32 in -> bf16 MFMA). Stores h in jv-PERMUTED
// B-fragment layout hTf[jbv][ft][lane][8]. Also emits per-row E=exp(s),
// F=exp(0.2 s).  (unchanged from R7, verified)
// ---------------------------------------------------------------------------
__global__ __launch_bounds__(256) void gat_h_kernel(
    const float* __restrict__ input,    // [8192][256] fp32
    const float* __restrict__ W,        // [256][64] fp32
    const float* __restrict__ a,        // [128] fp32
    bf16_t* __restrict__ hTf,           // [256][4][64][8] bf16, jv-frag layout
    float* __restrict__ e1g, float* __restrict__ f1g,
    float* __restrict__ e2g, float* __restrict__ f2g)
{
    alignas(16) __shared__ bf16_t in_lds[32][264];
    alignas(16) __shared__ bf16_t wt_lds[64][264];
    __shared__ float h_lds[32][65];

    const int t  = threadIdx.x;
    const int i0 = blockIdx.x * 32;

    #pragma unroll
    for (int v = 0; v < 8; v++) {
        int u  = v * 256 + t;
        int i  = u >> 6;
        int k4 = (u & 63) * 4;
        floatx4 x = *(const floatx4*)(input + (size_t)(i0 + i) * FIN + k4);
        bf16x4 b;
        #pragma unroll
        for (int e = 0; e < 4; e++) b[e] = (bf16_t)x[e];
        *(bf16x4*)(&in_lds[i][k4]) = b;
    }
    #pragma unroll
    for (int v = 0; v < 16; v++) {
        int u  = v * 256 + t;
        int k  = u >> 4;
        int f4 = (u & 15) * 4;
        floatx4 wv = *(const floatx4*)(W + k * FOUT + f4);
        #pragma unroll
        for (int e = 0; e < 4; e++) wt_lds[f4 + e][k] = (bf16_t)wv[e];
    }
    __syncthreads();

    const int wave = t >> 6;
    const int lane = t & 63;
    const int i16  = (wave & 1) * 16;
    const int f32  = (wave >> 1) * 32;
    const int lm   = lane & 15;
    const int lq   = lane >> 4;

    floatx4 acc0 = {0.f, 0.f, 0.f, 0.f};
    floatx4 acc1 = {0.f, 0.f, 0.f, 0.f};
    #pragma unroll
    for (int ks = 0; ks < 8; ks++) {
        int ko = ks * 32 + lq * 8;
        bf16x8 af = *(const bf16x8*)(&in_lds[i16 + lm][ko]);
        bf16x8 b0 = *(const bf16x8*)(&wt_lds[f32 + lm][ko]);
        bf16x8 b1 = *(const bf16x8*)(&wt_lds[f32 + 16 + lm][ko]);
        acc0 = __builtin_amdgcn_mfma_f32_16x16x32_bf16(af, b0, acc0, 0, 0, 0);
        acc1 = __builtin_amdgcn_mfma_f32_16x16x32_bf16(af, b1, acc1, 0, 0, 0);
    }

    // permuted hTf store. Lane holds h[i0 + d][f32+c*16+lm], d = i16+lq*4+r.
    // j = i0+d: G = i0>>8, w = d&3 = r, p = p0 + (d>>2), p0 = (i0&255)>>2.
    // slot: jbv = G*8 + r*2 + (p0>>5), lq' = (p0>>3)&3, e' = (i16>>2)+lq.
    {
        const int G    = i0 >> 8;
        const int p0   = (i0 & 255) >> 2;
        const int hi5  = p0 >> 5;
        const int lqp  = (p0 >> 3) & 3;
        const int enew = (i16 >> 2) + lq;
        #pragma unroll
        for (int c = 0; c < 2; c++) {
            floatx4 acc = c ? acc1 : acc0;
            int ft = (f32 >> 4) + c;
            #pragma unroll
            for (int r = 0; r < 4; r++) {
                int jbv = G * 8 + r * 2 + hi5;
                size_t idx = ((size_t)(jbv * 4 + ft) * 64 + lqp * 16 + lm) * 8 + enew;
                hTf[idx] = (bf16_t)acc[r];
            }
        }
    }
    // fp32 h tile into LDS for s1/s2
    #pragma unroll
    for (int c = 0; c < 2; c++) {
        floatx4 acc = c ? acc1 : acc0;
        #pragma unroll
        for (int r = 0; r < 4; r++)
            h_lds[i16 + lq * 4 + r][f32 + c * 16 + lm] = acc[r];
    }
    __syncthreads();

    if (t < 64) {
        int r   = t & 31;
        int sel = t >> 5;
        const float* av = a + sel * FOUT;
        float s = 0.f;
        #pragma unroll 8
        for (int f = 0; f < FOUT; f++) s += h_lds[r][f] * av[f];
        int gi = i0 + r;
        float E = expf(s);
        float F = expf(GAT_ALPHA * s);
        if (sel == 0) { e1g[gi] = E; f1g[gi] = F; }
        else          { e2g[gi] = E; f2g[gi] = F; }
    }
}

// ---------------------------------------------------------------------------
// Kernel B: attention + aggregation from the jv-ordered bit matrix.
// (unchanged from R7, verified)
// ---------------------------------------------------------------------------
__global__ __launch_bounds__(256, 4) void gat_att_kernel(
    const unsigned char* __restrict__ bits,  // [8192][1024] bytes, jv-order
    const bf16_t* __restrict__ hTf,          // [256][4][64][8] bf16 jv-frag
    const float* __restrict__ e1g, const float* __restrict__ f1g,
    const float* __restrict__ e2g, const float* __restrict__ f2g,
    float* __restrict__ pacc,                // [NSLICE][8192][64] fp32
    float* __restrict__ prs)                 // [NSLICE][8192] fp32
{
    __shared__ unsigned char bitsL[IB][128];    // 8 KB, XOR-swizzled granules
    __shared__ float e2l[JS], f2l[JS];          // 8 KB, jv-indexed

    const int t     = threadIdx.x;
    const int i0    = blockIdx.x * IB;
    const int slice = blockIdx.y;
    const int jbase = slice * JS;

    const int wave = t >> 6;
    const int lane = t & 63;
    const int lm   = lane & 15;
    const int lq   = lane >> 4;

    // ---- stage bits: rows i0..i0+63, window = 128 B/row ----
    #pragma unroll
    for (int h = 0; h < 2; h++) {
        int r0 = wave * 16 + h * 8;            // 8 rows per instr
        int r  = r0 + (lane >> 3);
        int g  = (lane & 7) ^ (r & 7);
        GLOAD16(bits + (size_t)(i0 + r) * 1024 + slice * 128 + g * 16,
                &bitsL[r0][0]);
    }
    // ---- stage e2/f2 with jv permutation (register path, once) ----
    {
        floatx4 ev = *(const floatx4*)(e2g + jbase + t * 4);
        floatx4 fv = *(const floatx4*)(f2g + jbase + t * 4);
        int base = (t >> 6) * 256 + (t & 63);
        #pragma unroll
        for (int e = 0; e < 4; e++) {
            e2l[base + e * 64] = ev[e];
            f2l[base + e * 64] = fv[e];
        }
    }
    __syncthreads();    // pack + LDS writes visible; the only barrier

    const int   row = wave * 16 + lm;          // block-local A-frag row
    const float E1  = e1g[i0 + row];
    const float F1  = f1g[i0 + row];

    floatx4 acc0 = {0.f,0.f,0.f,0.f}, acc1 = {0.f,0.f,0.f,0.f};
    floatx4 acc2 = {0.f,0.f,0.f,0.f}, acc3 = {0.f,0.f,0.f,0.f};
    floatx4 accR = {0.f,0.f,0.f,0.f};
    bf16x8 ones;
    #pragma unroll
    for (int e = 0; e < 8; e++) ones[e] = (bf16_t)1.0f;

    const bf16_t* hslice = hTf + (size_t)slice * NJB * 2048 + (size_t)lane * 8;

    #pragma unroll 8
    for (int jb = 0; jb < NJB; jb++) {
        // u32 word jb of this row's window (granule-XOR read, 2-way = free)
        int off = (((jb >> 2) ^ (row & 7)) << 4) | ((jb & 3) << 2);
        int wrd = *(const int*)(&bitsL[row][off]);
        unsigned bt = ((unsigned)wrd >> (lq * 8)) & 0xffu;   // v_bfe

        int jo = jb * 32 + lq * 8;
        floatx4 e2a = *(const floatx4*)(&e2l[jo]);
        floatx4 e2b = *(const floatx4*)(&e2l[jo + 4]);
        floatx4 f2a = *(const floatx4*)(&f2l[jo]);
        floatx4 f2b = *(const floatx4*)(&f2l[jo + 4]);
        bf16x8 frag;
        #pragma unroll
        for (int e = 0; e < 4; e++) {
            float w0 = fmaxf(E1 * e2a[e], F1 * f2a[e]);
            frag[e]     = (bt & (1u << e))       ? (bf16_t)w0 : (bf16_t)0.f;
            float w1 = fmaxf(E1 * e2b[e], F1 * f2b[e]);
            frag[e + 4] = (bt & (1u << (e + 4))) ? (bf16_t)w1 : (bf16_t)0.f;
        }

        const bf16_t* hb = hslice + (size_t)jb * 2048;
        bf16x8 b0 = *(const bf16x8*)(hb);
        bf16x8 b1 = *(const bf16x8*)(hb + 512);
        bf16x8 b2 = *(const bf16x8*)(hb + 1024);
        bf16x8 b3 = *(const bf16x8*)(hb + 1536);
        acc0 = __builtin_amdgcn_mfma_f32_16x16x32_bf16(frag, b0, acc0, 0, 0, 0);
        acc1 = __builtin_amdgcn_mfma_f32_16x16x32_bf16(frag, b1, acc1, 0, 0, 0);
        acc2 = __builtin_amdgcn_mfma_f32_16x16x32_bf16(frag, b2, acc2, 0, 0, 0);
        acc3 = __builtin_amdgcn_mfma_f32_16x16x32_bf16(frag, b3, acc3, 0, 0, 0);
        accR = __builtin_amdgcn_mfma_f32_16x16x32_bf16(frag, ones, accR, 0, 0, 0);
    }

    if (lm == 0) {
        #pragma unroll
        for (int r = 0; r < 4; r++)
            prs[(size_t)slice * NN + i0 + wave * 16 + lq * 4 + r] = accR[r];
    }

    float* pa = pacc + (size_t)slice * NN * FOUT
                     + (size_t)(i0 + wave * 16) * FOUT;
    #pragma unroll
    for (int ft = 0; ft < 4; ft++) {
        floatx4 acc = (ft == 0) ? acc0 : (ft == 1) ? acc1
                    : (ft == 2) ? acc2 : acc3;
        #pragma unroll
        for (int r = 0; r < 4; r++)
            pa[(size_t)(lq * 4 + r) * FOUT + ft * 16 + lm] = acc[r];
    }
}

// ---------------------------------------------------------------------------
// Kernel C: combine NSLICE partials, normalize, ELU, store fp32 output.
// ---------------------------------------------------------------------------
__global__ __launch_bounds__(256) void gat_combine_kernel(
    const float* __restrict__ pacc,     // [NSLICE][8192][64]
    const float* __restrict__ prs,      // [NSLICE][8192]
    float* __restrict__ out)            // [8192][64]
{
    int idx = blockIdx.x * 256 + threadIdx.x;
    int i   = idx >> 4;
    floatx4 s = {0.f, 0.f, 0.f, 0.f};
    float rs  = 0.f;
    #pragma unroll
    for (int p = 0; p < NSLICE; p++) {
        floatx4 v = *(const floatx4*)(pacc + (size_t)p * NN * FOUT + (size_t)idx * 4);
        s += v;
        rs += prs[p * NN + i];
    }
    float rinv = (rs > 0.f) ? 1.0f / rs : 0.f;
    floatx4 r;
    #pragma unroll
    for (int e = 0; e < 4; e++) {
        float x = s[e] * rinv;
        r[e] = (x > 0.f) ? x : (expf(x) - 1.0f);
    }
    *(floatx4*)(out + (size_t)idx * 4) = r;
}

// ---------------------------------------------------------------------------
extern "C" void kernel_launch(void* const* d_in, const int* in_sizes, int n_in,
                              void* d_out, int out_size, void* d_ws, size_t ws_size,
                              hipStream_t stream) {
    const float* input = (const float*)d_in[0];     // [8192][256] fp32
    const int*   adj   = (const int*)d_in[1];       // [8192][8192] int32
    const float* W     = (const float*)d_in[2];     // [256][64] fp32
    const float* a     = (const float*)d_in[3];     // [128] fp32
    float*       out   = (float*)d_out;             // [8192][64] fp32

    char* ws = (char*)d_ws;
    bf16_t* hTf = (bf16_t*)ws;                      // 1 MiB (jv-frag layout)
    float*  e1g = (float*)(ws + (1 << 20));
    float*  f1g = e1g + NN;
    float*  e2g = f1g + NN;
    float*  f2g = e2g + NN;
    unsigned long long* bitsw = (unsigned long long*)(f2g + NN);   // 8 MiB
    float*  pacc = (float*)((char*)bitsw + (size_t)NN * 128 * 8);  // 16 MiB
    float*  prs  = pacc + (size_t)NSLICE * NN * FOUT;              // 256 KiB

    gat_pack_kernel<<<NN / 4, 256, 0, stream>>>(adj, bitsw);
    gat_h_kernel<<<NN / 32, 256, 0, stream>>>(input, W, a, hTf,
                                              e1g, f1g, e2g, f2g);
    dim3 gridB(NN / IB, NSLICE);
    gat_att_kernel<<<gridB, 256, 0, stream>>>((const unsigned char*)bitsw, hTf,
                                              e1g, f1g, e2g, f2g, pacc, prs);
    gat_combine_kernel<<<NN * FOUT / 4 / 256, 256, 0, stream>>>(pacc, prs, out);
}

// Round 9
// 382.991 us; speedup vs baseline: 1.0752x; 1.0038x over previous
//
#include <hip/hip_runtime.h>
#include <hip/hip_bf16.h>

typedef __bf16 bf16_t;
typedef __attribute__((ext_vector_type(8))) __bf16 bf16x8;
typedef __attribute__((ext_vector_type(4))) __bf16 bf16x4;
typedef __attribute__((ext_vector_type(4))) float floatx4;
typedef __attribute__((ext_vector_type(4))) int intx4;

#define NN 8192
#define FIN 256
#define FOUT 64
#define GAT_ALPHA 0.2f
#define NSLICE 8
#define JS (NN / NSLICE)     // 1024 j per slice
#define NJB (JS / 32)        // 32 MFMA K-tiles per slice
#define IB 64                // i-rows per block

// Permuted j-order ("jv"): real j = G*256 + p*4 + w  <->  jv = G*256 + w*64 + p.
// Ballot-natural; softmax num/denom are j-permutation-invariant as long as
// adj-bits, e2/f2, and h rows share the order. prs/pacc unaffected.

// global_load_lds: wave-uniform LDS base, per-lane global src, 16B/lane
typedef const __attribute__((address_space(1))) void gv_t;
typedef __attribute__((address_space(3))) void lv_t;
#define GLOAD16(gp, lp) \
    __builtin_amdgcn_global_load_lds((gv_t*)(gp), (lv_t*)(lp), 16, 0, 0)

// ---------------------------------------------------------------------------
// Kernel P: ballot pack, nt loads, MAX READ ILP. Per wave half-row: issue
// ALL 16 nt loads back-to-back (16 KB in flight, 64 staging VGPRs, all
// indices compile-time after unroll), THEN run the ballot/select chain.
// Removes the v_cmp/vcc serialization between load-issue groups that capped
// R8 at 4 outstanding. adj (256 MB, zero-reuse) -> [8192][128] u64 jv-order.
// ---------------------------------------------------------------------------
__global__ __launch_bounds__(256) void gat_pack_kernel(
    const int* __restrict__ adj,
    unsigned long long* __restrict__ bits)      // [8192][128] u64, jv-order
{
    const int wave = threadIdx.x >> 6;
    const int lane = threadIdx.x & 63;
    const int row  = blockIdx.x * 4 + wave;
    const int* rp  = adj + (size_t)row * NN + lane * 4;

    #pragma unroll
    for (int half = 0; half < 2; half++) {      // 16 groups = 16 KB each
        intx4 v0  = __builtin_nontemporal_load((const intx4*)(rp + (half*16+ 0)*256));
        intx4 v1  = __builtin_nontemporal_load((const intx4*)(rp + (half*16+ 1)*256));
        intx4 v2  = __builtin_nontemporal_load((const intx4*)(rp + (half*16+ 2)*256));
        intx4 v3  = __builtin_nontemporal_load((const intx4*)(rp + (half*16+ 3)*256));
        intx4 v4  = __builtin_nontemporal_load((const intx4*)(rp + (half*16+ 4)*256));
        intx4 v5  = __builtin_nontemporal_load((const intx4*)(rp + (half*16+ 5)*256));
        intx4 v6  = __builtin_nontemporal_load((const intx4*)(rp + (half*16+ 6)*256));
        intx4 v7  = __builtin_nontemporal_load((const intx4*)(rp + (half*16+ 7)*256));
        intx4 v8  = __builtin_nontemporal_load((const intx4*)(rp + (half*16+ 8)*256));
        intx4 v9  = __builtin_nontemporal_load((const intx4*)(rp + (half*16+ 9)*256));
        intx4 v10 = __builtin_nontemporal_load((const intx4*)(rp + (half*16+10)*256));
        intx4 v11 = __builtin_nontemporal_load((const intx4*)(rp + (half*16+11)*256));
        intx4 v12 = __builtin_nontemporal_load((const intx4*)(rp + (half*16+12)*256));
        intx4 v13 = __builtin_nontemporal_load((const intx4*)(rp + (half*16+13)*256));
        intx4 v14 = __builtin_nontemporal_load((const intx4*)(rp + (half*16+14)*256));
        intx4 v15 = __builtin_nontemporal_load((const intx4*)(rp + (half*16+15)*256));

        unsigned long long acc = 0;
        #pragma unroll
        for (int g = 0; g < 16; g++) {
            intx4 v = (g ==  0) ? v0  : (g ==  1) ? v1  : (g ==  2) ? v2
                    : (g ==  3) ? v3  : (g ==  4) ? v4  : (g ==  5) ? v5
                    : (g ==  6) ? v6  : (g ==  7) ? v7  : (g ==  8) ? v8
                    : (g ==  9) ? v9  : (g == 10) ? v10 : (g == 11) ? v11
                    : (g == 12) ? v12 : (g == 13) ? v13 : (g == 14) ? v14 : v15;
            unsigned long long m0 = __ballot(v[0] > 0);
            unsigned long long m1 = __ballot(v[1] > 0);
            unsigned long long m2 = __ballot(v[2] > 0);
            unsigned long long m3 = __ballot(v[3] > 0);
            if ((lane >> 2) == g) {
                acc = (lane & 1) ? ((lane & 2) ? m3 : m1)
                                 : ((lane & 2) ? m2 : m0);
            }
        }
        // lane = g*4 + w  ->  u64 index G_global*4 + w  (G = half*16+g)
        bits[(size_t)row * 128 + half * 64 + lane] = acc;
    }
}

// ---------------------------------------------------------------------------
// Kernel A: h = input @ W (fp32 in -> bf16 MFMA). Stores h in jv-PERMUTED
// B-fragment layout hTf[jbv][ft][lane][8]. Also emits per-row E=exp(s),
// F=exp(0.2 s).  (unchanged from R7/R8, verified)
// ---------------------------------------------------------------------------
__global__ __launch_bounds__(256) void gat_h_kernel(
    const float* __restrict__ input,    // [8192][256] fp32
    const float* __restrict__ W,        // [256][64] fp32
    const float* __restrict__ a,        // [128] fp32
    bf16_t* __restrict__ hTf,           // [256][4][64][8] bf16, jv-frag layout
    float* __restrict__ e1g, float* __restrict__ f1g,
    float* __restrict__ e2g, float* __restrict__ f2g)
{
    alignas(16) __shared__ bf16_t in_lds[32][264];
    alignas(16) __shared__ bf16_t wt_lds[64][264];
    __shared__ float h_lds[32][65];

    const int t  = threadIdx.x;
    const int i0 = blockIdx.x * 32;

    #pragma unroll
    for (int v = 0; v < 8; v++) {
        int u  = v * 256 + t;
        int i  = u >> 6;
        int k4 = (u & 63) * 4;
        floatx4 x = *(const floatx4*)(input + (size_t)(i0 + i) * FIN + k4);
        bf16x4 b;
        #pragma unroll
        for (int e = 0; e < 4; e++) b[e] = (bf16_t)x[e];
        *(bf16x4*)(&in_lds[i][k4]) = b;
    }
    #pragma unroll
    for (int v = 0; v < 16; v++) {
        int u  = v * 256 + t;
        int k  = u >> 4;
        int f4 = (u & 15) * 4;
        floatx4 wv = *(const floatx4*)(W + k * FOUT + f4);
        #pragma unroll
        for (int e = 0; e < 4; e++) wt_lds[f4 + e][k] = (bf16_t)wv[e];
    }
    __syncthreads();

    const int wave = t >> 6;
    const int lane = t & 63;
    const int i16  = (wave & 1) * 16;
    const int f32  = (wave >> 1) * 32;
    const int lm   = lane & 15;
    const int lq   = lane >> 4;

    floatx4 acc0 = {0.f, 0.f, 0.f, 0.f};
    floatx4 acc1 = {0.f, 0.f, 0.f, 0.f};
    #pragma unroll
    for (int ks = 0; ks < 8; ks++) {
        int ko = ks * 32 + lq * 8;
        bf16x8 af = *(const bf16x8*)(&in_lds[i16 + lm][ko]);
        bf16x8 b0 = *(const bf16x8*)(&wt_lds[f32 + lm][ko]);
        bf16x8 b1 = *(const bf16x8*)(&wt_lds[f32 + 16 + lm][ko]);
        acc0 = __builtin_amdgcn_mfma_f32_16x16x32_bf16(af, b0, acc0, 0, 0, 0);
        acc1 = __builtin_amdgcn_mfma_f32_16x16x32_bf16(af, b1, acc1, 0, 0, 0);
    }

    // permuted hTf store. Lane holds h[i0 + d][f32+c*16+lm], d = i16+lq*4+r.
    // j = i0+d: G = i0>>8, w = d&3 = r, p = p0 + (d>>2), p0 = (i0&255)>>2.
    // slot: jbv = G*8 + r*2 + (p0>>5), lq' = (p0>>3)&3, e' = (i16>>2)+lq.
    {
        const int G    = i0 >> 8;
        const int p0   = (i0 & 255) >> 2;
        const int hi5  = p0 >> 5;
        const int lqp  = (p0 >> 3) & 3;
        const int enew = (i16 >> 2) + lq;
        #pragma unroll
        for (int c = 0; c < 2; c++) {
            floatx4 acc = c ? acc1 : acc0;
            int ft = (f32 >> 4) + c;
            #pragma unroll
            for (int r = 0; r < 4; r++) {
                int jbv = G * 8 + r * 2 + hi5;
                size_t idx = ((size_t)(jbv * 4 + ft) * 64 + lqp * 16 + lm) * 8 + enew;
                hTf[idx] = (bf16_t)acc[r];
            }
        }
    }
    // fp32 h tile into LDS for s1/s2
    #pragma unroll
    for (int c = 0; c < 2; c++) {
        floatx4 acc = c ? acc1 : acc0;
        #pragma unroll
        for (int r = 0; r < 4; r++)
            h_lds[i16 + lq * 4 + r][f32 + c * 16 + lm] = acc[r];
    }
    __syncthreads();

    if (t < 64) {
        int r   = t & 31;
        int sel = t >> 5;
        const float* av = a + sel * FOUT;
        float s = 0.f;
        #pragma unroll 8
        for (int f = 0; f < FOUT; f++) s += h_lds[r][f] * av[f];
        int gi = i0 + r;
        float E = expf(s);
        float F = expf(GAT_ALPHA * s);
        if (sel == 0) { e1g[gi] = E; f1g[gi] = F; }
        else          { e2g[gi] = E; f2g[gi] = F; }
    }
}

// ---------------------------------------------------------------------------
// Kernel B: attention + aggregation from the jv-ordered bit matrix.
// (unchanged from R7/R8, verified)
// ---------------------------------------------------------------------------
__global__ __launch_bounds__(256, 4) void gat_att_kernel(
    const unsigned char* __restrict__ bits,  // [8192][1024] bytes, jv-order
    const bf16_t* __restrict__ hTf,          // [256][4][64][8] bf16 jv-frag
    const float* __restrict__ e1g, const float* __restrict__ f1g,
    const float* __restrict__ e2g, const float* __restrict__ f2g,
    float* __restrict__ pacc,                // [NSLICE][8192][64] fp32
    float* __restrict__ prs)                 // [NSLICE][8192] fp32
{
    __shared__ unsigned char bitsL[IB][128];    // 8 KB, XOR-swizzled granules
    __shared__ float e2l[JS], f2l[JS];          // 8 KB, jv-indexed

    const int t     = threadIdx.x;
    const int i0    = blockIdx.x * IB;
    const int slice = blockIdx.y;
    const int jbase = slice * JS;

    const int wave = t >> 6;
    const int lane = t & 63;
    const int lm   = lane & 15;
    const int lq   = lane >> 4;

    // ---- stage bits: rows i0..i0+63, window = 128 B/row ----
    #pragma unroll
    for (int h = 0; h < 2; h++) {
        int r0 = wave * 16 + h * 8;            // 8 rows per instr
        int r  = r0 + (lane >> 3);
        int g  = (lane & 7) ^ (r & 7);
        GLOAD16(bits + (size_t)(i0 + r) * 1024 + slice * 128 + g * 16,
                &bitsL[r0][0]);
    }
    // ---- stage e2/f2 with jv permutation (register path, once) ----
    {
        floatx4 ev = *(const floatx4*)(e2g + jbase + t * 4);
        floatx4 fv = *(const floatx4*)(f2g + jbase + t * 4);
        int base = (t >> 6) * 256 + (t & 63);
        #pragma unroll
        for (int e = 0; e < 4; e++) {
            e2l[base + e * 64] = ev[e];
            f2l[base + e * 64] = fv[e];
        }
    }
    __syncthreads();    // pack + LDS writes visible; the only barrier

    const int   row = wave * 16 + lm;          // block-local A-frag row
    const float E1  = e1g[i0 + row];
    const float F1  = f1g[i0 + row];

    floatx4 acc0 = {0.f,0.f,0.f,0.f}, acc1 = {0.f,0.f,0.f,0.f};
    floatx4 acc2 = {0.f,0.f,0.f,0.f}, acc3 = {0.f,0.f,0.f,0.f};
    floatx4 accR = {0.f,0.f,0.f,0.f};
    bf16x8 ones;
    #pragma unroll
    for (int e = 0; e < 8; e++) ones[e] = (bf16_t)1.0f;

    const bf16_t* hslice = hTf + (size_t)slice * NJB * 2048 + (size_t)lane * 8;

    #pragma unroll 8
    for (int jb = 0; jb < NJB; jb++) {
        // u32 word jb of this row's window (granule-XOR read, 2-way = free)
        int off = (((jb >> 2) ^ (row & 7)) << 4) | ((jb & 3) << 2);
        int wrd = *(const int*)(&bitsL[row][off]);
        unsigned bt = ((unsigned)wrd >> (lq * 8)) & 0xffu;   // v_bfe

        int jo = jb * 32 + lq * 8;
        floatx4 e2a = *(const floatx4*)(&e2l[jo]);
        floatx4 e2b = *(const floatx4*)(&e2l[jo + 4]);
        floatx4 f2a = *(const floatx4*)(&f2l[jo]);
        floatx4 f2b = *(const floatx4*)(&f2l[jo + 4]);
        bf16x8 frag;
        #pragma unroll
        for (int e = 0; e < 4; e++) {
            float w0 = fmaxf(E1 * e2a[e], F1 * f2a[e]);
            frag[e]     = (bt & (1u << e))       ? (bf16_t)w0 : (bf16_t)0.f;
            float w1 = fmaxf(E1 * e2b[e], F1 * f2b[e]);
            frag[e + 4] = (bt & (1u << (e + 4))) ? (bf16_t)w1 : (bf16_t)0.f;
        }

        const bf16_t* hb = hslice + (size_t)jb * 2048;
        bf16x8 b0 = *(const bf16x8*)(hb);
        bf16x8 b1 = *(const bf16x8*)(hb + 512);
        bf16x8 b2 = *(const bf16x8*)(hb + 1024);
        bf16x8 b3 = *(const bf16x8*)(hb + 1536);
        acc0 = __builtin_amdgcn_mfma_f32_16x16x32_bf16(frag, b0, acc0, 0, 0, 0);
        acc1 = __builtin_amdgcn_mfma_f32_16x16x32_bf16(frag, b1, acc1, 0, 0, 0);
        acc2 = __builtin_amdgcn_mfma_f32_16x16x32_bf16(frag, b2, acc2, 0, 0, 0);
        acc3 = __builtin_amdgcn_mfma_f32_16x16x32_bf16(frag, b3, acc3, 0, 0, 0);
        accR = __builtin_amdgcn_mfma_f32_16x16x32_bf16(frag, ones, accR, 0, 0, 0);
    }

    if (lm == 0) {
        #pragma unroll
        for (int r = 0; r < 4; r++)
            prs[(size_t)slice * NN + i0 + wave * 16 + lq * 4 + r] = accR[r];
    }

    float* pa = pacc + (size_t)slice * NN * FOUT
                     + (size_t)(i0 + wave * 16) * FOUT;
    #pragma unroll
    for (int ft = 0; ft < 4; ft++) {
        floatx4 acc = (ft == 0) ? acc0 : (ft == 1) ? acc1
                    : (ft == 2) ? acc2 : acc3;
        #pragma unroll
        for (int r = 0; r < 4; r++)
            pa[(size_t)(lq * 4 + r) * FOUT + ft * 16 + lm] = acc[r];
    }
}

// ---------------------------------------------------------------------------
// Kernel C: combine NSLICE partials, normalize, ELU, store fp32 output.
// ---------------------------------------------------------------------------
__global__ __launch_bounds__(256) void gat_combine_kernel(
    const float* __restrict__ pacc,     // [NSLICE][8192][64]
    const float* __restrict__ prs,      // [NSLICE][8192]
    float* __restrict__ out)            // [8192][64]
{
    int idx = blockIdx.x * 256 + threadIdx.x;
    int i   = idx >> 4;
    floatx4 s = {0.f, 0.f, 0.f, 0.f};
    float rs  = 0.f;
    #pragma unroll
    for (int p = 0; p < NSLICE; p++) {
        floatx4 v = *(const floatx4*)(pacc + (size_t)p * NN * FOUT + (size_t)idx * 4);
        s += v;
        rs += prs[p * NN + i];
    }
    float rinv = (rs > 0.f) ? 1.0f / rs : 0.f;
    floatx4 r;
    #pragma unroll
    for (int e = 0; e < 4; e++) {
        float x = s[e] * rinv;
        r[e] = (x > 0.f) ? x : (expf(x) - 1.0f);
    }
    *(floatx4*)(out + (size_t)idx * 4) = r;
}

// ---------------------------------------------------------------------------
extern "C" void kernel_launch(void* const* d_in, const int* in_sizes, int n_in,
                              void* d_out, int out_size, void* d_ws, size_t ws_size,
                              hipStream_t stream) {
    const float* input = (const float*)d_in[0];     // [8192][256] fp32
    const int*   adj   = (const int*)d_in[1];       // [8192][8192] int32
    const float* W     = (const float*)d_in[2];     // [256][64] fp32
    const float* a     = (const float*)d_in[3];     // [128] fp32
    float*       out   = (float*)d_out;             // [8192][64] fp32

    char* ws = (char*)d_ws;
    bf16_t* hTf = (bf16_t*)ws;                      // 1 MiB (jv-frag layout)
    float*  e1g = (float*)(ws + (1 << 20));
    float*  f1g = e1g + NN;
    float*  e2g = f1g + NN;
    float*  f2g = e2g + NN;
    unsigned long long* bitsw = (unsigned long long*)(f2g + NN);   // 8 MiB
    float*  pacc = (float*)((char*)bitsw + (size_t)NN * 128 * 8);  // 16 MiB
    float*  prs  = pacc + (size_t)NSLICE * NN * FOUT;              // 256 KiB

    gat_pack_kernel<<<NN / 4, 256, 0, stream>>>(adj, bitsw);
    gat_h_kernel<<<NN / 32, 256, 0, stream>>>(input, W, a, hTf,
                                              e1g, f1g, e2g, f2g);
    dim3 gridB(NN / IB, NSLICE);
    gat_att_kernel<<<gridB, 256, 0, stream>>>((const unsigned char*)bitsw, hTf,
                                              e1g, f1g, e2g, f2g, pacc, prs);
    gat_combine_kernel<<<NN * FOUT / 4 / 256, 256, 0, stream>>>(pacc, prs, out);
}